// Round 2
// baseline (225.109 us; speedup 1.0000x reference)
//
#include <hip/hip_runtime.h>
#include <math.h>

#define COS_EPS 1e-8f

typedef float vfloat4 __attribute__((ext_vector_type(4)));

__device__ __forceinline__ float dot4(vfloat4 a, vfloat4 b) {
    return fmaf(a.x, b.x, fmaf(a.y, b.y, fmaf(a.z, b.z, a.w * b.w)));
}

// ---------------------------------------------------------------------------
// R9: label-clustered processing. Counting-sort samples by label (3 tiny
// dispatches), then each wave handles a CONTIGUOUS run of 16 sorted samples.
// A label's ~6.5 samples now land in the same wave -> each 2KB proto row is
// fetched from HBM ~once (L1/L2 serves the re-reads) instead of ~6.5x.
// Predicted HBM traffic 270 -> ~165 MB.
// Quarter-wave mapping kept from R7: 16 lanes/sample, 4 samples/wave,
// 4-step butterfly reduces all 4 samples at once.
// ---------------------------------------------------------------------------

// S1: histogram of labels (avg 6.5 per bin -> negligible contention)
__global__ __launch_bounds__(256) void hist_kernel(
    const int* __restrict__ labels, int* __restrict__ hist, int B)
{
    int i = blockIdx.x * blockDim.x + threadIdx.x;
    if (i < B) atomicAdd(&hist[labels[i]], 1);
}

// S2: exclusive prefix sum over C bins, single block of 1024 threads
__global__ __launch_bounds__(1024) void scan_kernel(int* __restrict__ hist, int C)
{
    __shared__ int smem[1024];
    const int t = threadIdx.x;
    const int chunk = (C + 1023) >> 10;
    const int lo = t * chunk;
    const int hi = (lo + chunk < C) ? lo + chunk : C;

    int sum = 0;
    for (int i = lo; i < hi; ++i) sum += hist[i];
    smem[t] = sum;
    __syncthreads();

    // Hillis-Steele inclusive scan over 1024 partials
    for (int off = 1; off < 1024; off <<= 1) {
        int v = 0;
        if (t >= off) v = smem[t - off];
        __syncthreads();
        if (t >= off) smem[t] += v;
        __syncthreads();
    }

    int run = (t > 0) ? smem[t - 1] : 0;   // exclusive prefix of this chunk
    for (int i = lo; i < hi; ++i) {
        int v = hist[i];
        hist[i] = run;                      // bin start offset
        run += v;
    }
}

// S3: scatter sample indices into sorted order (offs consumed as counters)
__global__ __launch_bounds__(256) void scatter_kernel(
    const int* __restrict__ labels, int* __restrict__ offs,
    int* __restrict__ perm, int* __restrict__ slbl, int B)
{
    int i = blockIdx.x * blockDim.x + threadIdx.x;
    if (i < B) {
        int l = labels[i];
        int pos = atomicAdd(&offs[l], 1);
        perm[pos] = i;
        slbl[pos] = l;
    }
}

__global__ __launch_bounds__(256) void assignment_loss_kernel(
    const float* __restrict__ emb,      // [B, D]
    const float* __restrict__ protos,   // [C, D]
    const int*   __restrict__ perm,     // [B] label-sorted sample indices
    const int*   __restrict__ slbl,     // [B] sorted labels
    float*       __restrict__ part,     // [gridDim.x] partial sums
    int B, int D)
{
    const int lane = threadIdx.x & 63;
    const int grp  = lane >> 4;         // 0..3: which sample in the wave
    const int gl   = lane & 15;         // lane within group
    const int wib  = threadIdx.x >> 6;
    const int wpb  = blockDim.x >> 6;
    const int gw   = blockIdx.x * wpb + wib;
    const int nw   = gridDim.x * wpb;

    float local = 0.0f;

    if (D == 512 && (B % (4 * nw)) == 0) {
        const int spw   = B / nw;           // samples per wave (16)
        const int iters = spw >> 2;         // 4
        int j   = gw * spw + grp;           // contiguous run of sorted samples
        int s   = perm[j];
        int lbl = slbl[j];

        for (int i = 0; i < iters; ++i) {
            const int j_next = j + 4;
            int s_next = 0, lbl_next = 0;
            if (i + 1 < iters) { s_next = perm[j_next]; lbl_next = slbl[j_next]; }

            const vfloat4* e = (const vfloat4*)(emb    + (size_t)s   * 512);
            const vfloat4* p = (const vfloat4*)(protos + (size_t)lbl * 512);

            // 16 independent loads: 4 rows x 4KB in flight before any use.
            // emb single-use -> nt; protos reused within wave -> cacheable.
            vfloat4 ev[8], pv[8];
            #pragma unroll
            for (int c = 0; c < 8; ++c) ev[c] = __builtin_nontemporal_load(&e[c * 16 + gl]);
            #pragma unroll
            for (int c = 0; c < 8; ++c) pv[c] = p[c * 16 + gl];

            float dot = 0.f, esq = 0.f, psq = 0.f;
            #pragma unroll
            for (int c = 0; c < 8; ++c) {
                dot += dot4(ev[c], pv[c]);
                esq += dot4(ev[c], ev[c]);
                psq += dot4(pv[c], pv[c]);
            }

            // 4-step butterfly within each 16-lane group (4 samples at once)
            #pragma unroll
            for (int off = 8; off > 0; off >>= 1) {
                dot += __shfl_xor(dot, off, 64);
                esq += __shfl_xor(esq, off, 64);
                psq += __shfl_xor(psq, off, 64);
            }

            if (gl == 0) {
                float en = fmaxf(sqrtf(esq), COS_EPS);  // torch eps semantics
                float pn = fmaxf(sqrtf(psq), COS_EPS);
                local += dot / (en * pn);
            }

            j = j_next; s = s_next; lbl = lbl_next;
        }
    } else {
        // generic fallback: wave-per-sample over sorted order, D multiple of 256
        const int nchunks = D >> 8;
        for (int jj = gw; jj < B; jj += nw) {
            const int smp = perm[jj];
            const int l   = slbl[jj];
            const vfloat4* e = (const vfloat4*)(emb    + (size_t)smp * (size_t)D);
            const vfloat4* p = (const vfloat4*)(protos + (size_t)l   * (size_t)D);
            float dot = 0.f, esq = 0.f, psq = 0.f;
            for (int c = 0; c < nchunks; ++c) {
                vfloat4 ev = __builtin_nontemporal_load(&e[c * 64 + lane]);
                vfloat4 pv = p[c * 64 + lane];
                dot += dot4(ev, pv);
                esq += dot4(ev, ev);
                psq += dot4(pv, pv);
            }
            #pragma unroll
            for (int off = 32; off > 0; off >>= 1) {
                dot += __shfl_xor(dot, off, 64);
                esq += __shfl_xor(esq, off, 64);
                psq += __shfl_xor(psq, off, 64);
            }
            if (lane == 0) {
                float en = fmaxf(sqrtf(esq), COS_EPS);
                float pn = fmaxf(sqrtf(psq), COS_EPS);
                local += dot / (en * pn);
            }
        }
    }

    // full-wave butterfly, LDS across waves, one plain store per block
    #pragma unroll
    for (int off = 32; off > 0; off >>= 1) local += __shfl_xor(local, off, 64);

    __shared__ float smem[8];
    if (lane == 0) smem[wib] = local;
    __syncthreads();
    if (threadIdx.x == 0) {
        float bs = 0.0f;
        for (int w = 0; w < wpb; ++w) bs += smem[w];
        part[blockIdx.x] = bs;
    }
}

__global__ __launch_bounds__(256) void assignment_loss_finalize(
    const float* __restrict__ part,
    float*       __restrict__ out,
    int nparts, float invB)
{
    float s = 0.0f;
    for (int i = threadIdx.x; i < nparts; i += 256) s += part[i];
    #pragma unroll
    for (int off = 32; off > 0; off >>= 1) s += __shfl_xor(s, off, 64);

    __shared__ float smem[4];
    const int lane = threadIdx.x & 63;
    const int wib  = threadIdx.x >> 6;
    if (lane == 0) smem[wib] = s;
    __syncthreads();
    if (threadIdx.x == 0) {
        float t = smem[0] + smem[1] + smem[2] + smem[3];
        out[0] = 1.0f - t * invB;
    }
}

extern "C" void kernel_launch(void* const* d_in, const int* in_sizes, int n_in,
                              void* d_out, int out_size, void* d_ws, size_t ws_size,
                              hipStream_t stream) {
    const float* emb    = (const float*)d_in[0];   // [B, D] float32
    const int*   labels = (const int*)  d_in[1];   // [B] (int32 on device, jax x64 off)
    const float* protos = (const float*)d_in[2];   // [C, D] float32
    float*       out    = (float*)d_out;           // scalar float32

    const int B = in_sizes[1];
    const int D = in_sizes[0] / B;                 // 512
    const int C = in_sizes[2] / D;                 // 10000

    // workspace layout
    int*   hist = (int*)d_ws;                      // [C] -> becomes offsets
    int*   perm = hist + C;                        // [B]
    int*   slbl = perm + B;                        // [B]
    float* part = (float*)(slbl + B);              // [grid]

    hipMemsetAsync(hist, 0, (size_t)C * sizeof(int), stream);

    const int block = 256;
    const int bgrid = (B + block - 1) / block;     // 256 blocks for B=65536
    hist_kernel   <<<bgrid, block, 0, stream>>>(labels, hist, B);
    scan_kernel   <<<1, 1024, 0, stream>>>(hist, C);
    scatter_kernel<<<bgrid, block, 0, stream>>>(labels, hist, perm, slbl, B);

    const int grid = 1024;                         // 4096 waves; occupancy non-binding (R6)
    assignment_loss_kernel<<<grid, block, 0, stream>>>(emb, protos, perm, slbl, part, B, D);
    assignment_loss_finalize<<<1, block, 0, stream>>>(part, out, grid, 1.0f / (float)B);
}